// Round 2
// baseline (191.411 us; speedup 1.0000x reference)
//
#include <hip/hip_runtime.h>

// SimpleRelativeAttention collapses twice:
// 1. einsum 'bnqk,bnqe->bnqe' multiplies v by softmax row-sums (==1) -> attention
//    is an identity on v. rel_table/rel_index/q/k are dead.
// 2. out = x @ Wv @ Wproj + (b_v @ Wproj + b_proj); fold W_c = Wv @ Wproj
//    (1024^3 mini-GEMM) so the hot path is ONE 4096x1024x1024 GEMM.

#define DIMC 1024
#define MTOT 4096   // BATCH * SEQ

__device__ __forceinline__ unsigned short f2bf(float f) {
  unsigned u = __float_as_uint(f);
  u += 0x7FFFu + ((u >> 16) & 1u);   // round-to-nearest-even
  return (unsigned short)(u >> 16);
}

typedef __attribute__((ext_vector_type(8))) short short8;
typedef __attribute__((ext_vector_type(4))) float floatx4;

__device__ __forceinline__ void async_copy16(const unsigned short* g, unsigned short* l) {
  __builtin_amdgcn_global_load_lds(
      (const __attribute__((address_space(1))) unsigned int*)g,
      (__attribute__((address_space(3))) unsigned int*)l,
      16, 0, 0);
}

// fp32 -> bf16 elementwise, 4 elems/thread (contiguous)
__global__ void cast_bf16_kernel(const float* __restrict__ in,
                                 unsigned short* __restrict__ out) {
  int i = (blockIdx.x * 256 + threadIdx.x) * 4;
  float4 f = *(const float4*)(in + i);
  ushort4 o;
  o.x = f2bf(f.x); o.y = f2bf(f.y); o.z = f2bf(f.z); o.w = f2bf(f.w);
  *(ushort4*)(out + i) = o;
}

// out[r][c] = in[r*stride + col0 + c], out is [1024][1024] bf16 (no transpose)
__global__ void cast_slice_kernel(const float* __restrict__ in, int stride,
                                  int col0, unsigned short* __restrict__ out) {
  int i4 = blockIdx.x * 256 + threadIdx.x;      // one float4 per thread
  int r = i4 >> 8;                              // 256 groups of 4 per row
  int c = (i4 & 255) * 4;
  float4 f = *(const float4*)(in + (size_t)r * stride + col0 + c);
  ushort4 o;
  o.x = f2bf(f.x); o.y = f2bf(f.y); o.z = f2bf(f.z); o.w = f2bf(f.w);
  *(ushort4*)(out + (size_t)r * DIMC + c) = o;
}

// out[n][k] = in[k*stride + col0 + n]; out [DIMC][DIMC] bf16 row-major
__global__ void transpose_cast_kernel(const float* __restrict__ in, int stride,
                                      int col0, unsigned short* __restrict__ out) {
  __shared__ float tile[32][33];
  const int t = threadIdx.x;
  const int tx = t & 31, ty = t >> 5;
  const int bx = blockIdx.x, by = blockIdx.y;
#pragma unroll
  for (int r = 0; r < 4; ++r) {
    int kl = ty + r * 8;
    tile[kl][tx] = in[(size_t)(by * 32 + kl) * stride + col0 + bx * 32 + tx];
  }
  __syncthreads();
#pragma unroll
  for (int r = 0; r < 4; ++r) {
    int nl = ty + r * 8;
    out[(size_t)(bx * 32 + nl) * DIMC + by * 32 + tx] = f2bf(tile[tx][nl]);
  }
}

// b_c[n] = sum_j b_v[j] * w_proj[j][n] + b_proj[n]
__global__ void bias_combine_kernel(const float* __restrict__ b_v,
                                    const float* __restrict__ w_proj,
                                    const float* __restrict__ b_proj,
                                    float* __restrict__ b_c) {
  __shared__ float red[256];
  const int t = threadIdx.x;
  const int n = blockIdx.x * 64 + (t & 63);
  const int q = t >> 6;
  float s = 0.f;
  for (int j = q * 256; j < q * 256 + 256; ++j)
    s += b_v[j] * w_proj[(size_t)j * DIMC + n];
  red[t] = s;
  __syncthreads();
  if (q == 0) b_c[n] = red[t] + red[t + 64] + red[t + 128] + red[t + 192] + b_proj[n];
}

// C[M,N] = A[M,K] @ Bt[N,K]^T (+ bias[N])
// 64x128 block tile, BK=64, 256 threads = 4 waves, each wave 64x32 (4x2 frags).
// LDS chunk layout is forced by global_load_lds (chunk c -> offset c*16B), so
// bank conflicts are broken by XOR-swizzling the k-chunk on the GLOBAL side:
// chunk c holds global (row=c>>3, kc=(c&7)^(row&7)). Fragment reads then hit
// all 32 banks (2-way alias only, free per m136), staging stays coalesced
// (permutation within a 128B row segment).
template <bool BF16_OUT>
__global__ __launch_bounds__(256, 2) void gemm_bt_kernel(
    const unsigned short* __restrict__ A,   // [M,K] bf16
    const unsigned short* __restrict__ Bt,  // [N,K] bf16
    const float* __restrict__ bias,         // [N] or nullptr
    void* __restrict__ Cout, int M, int N, int K) {
  __shared__ __align__(16) unsigned short As[64 * 64];    // 8 KB
  __shared__ __align__(16) unsigned short Bs[128 * 64];   // 16 KB
  const int tid = threadIdx.x;
  const int wv = tid >> 6;
  const int lane = tid & 63;
  const int m0 = blockIdx.y * 64;
  const int n0 = blockIdx.x * 128;

  floatx4 acc[4][2] = {};

  // swizzled k-chunk for staging (same for all i since i*32 % 8 == 0)
  const int srow = tid >> 3;                       // 0..31
  const int skc = (tid & 7) ^ (srow & 7);          // swizzled k-chunk 0..7
  const unsigned short* Ag0 = A + (size_t)(m0 + srow) * K + skc * 8;
  const unsigned short* Ag1 = A + (size_t)(m0 + 32 + srow) * K + skc * 8;
  const unsigned short* Bg0 = Bt + (size_t)(n0 + srow) * K + skc * 8;
  const unsigned short* Bg1 = Bt + (size_t)(n0 + 32 + srow) * K + skc * 8;
  const unsigned short* Bg2 = Bt + (size_t)(n0 + 64 + srow) * K + skc * 8;
  const unsigned short* Bg3 = Bt + (size_t)(n0 + 96 + srow) * K + skc * 8;
  unsigned short* AsW0 = As + (0 * 256 + wv * 64) * 8;   // HW adds lane*16B
  unsigned short* AsW1 = As + (1 * 256 + wv * 64) * 8;
  unsigned short* BsW0 = Bs + (0 * 256 + wv * 64) * 8;
  unsigned short* BsW1 = Bs + (1 * 256 + wv * 64) * 8;
  unsigned short* BsW2 = Bs + (2 * 256 + wv * 64) * 8;
  unsigned short* BsW3 = Bs + (3 * 256 + wv * 64) * 8;

  const int lr = lane & 15;
  const int qr = lane >> 4;
  const int lx = lr & 7;   // swizzle key for fragment reads

  for (int k0 = 0; k0 < K; k0 += 64) {
    async_copy16(Ag0 + k0, AsW0);
    async_copy16(Ag1 + k0, AsW1);
    async_copy16(Bg0 + k0, BsW0);
    async_copy16(Bg1 + k0, BsW1);
    async_copy16(Bg2 + k0, BsW2);
    async_copy16(Bg3 + k0, BsW3);
    __syncthreads();   // drains vmcnt before barrier

    short8 a[2][4], b[2][2];
#pragma unroll
    for (int s = 0; s < 2; ++s) {
      const int kphys = ((s * 4 + qr) ^ lx) * 8;
#pragma unroll
      for (int mi = 0; mi < 4; ++mi)
        a[s][mi] = *(const short8*)(As + (mi * 16 + lr) * 64 + kphys);
#pragma unroll
      for (int ni = 0; ni < 2; ++ni)
        b[s][ni] = *(const short8*)(Bs + (wv * 32 + ni * 16 + lr) * 64 + kphys);
    }
#pragma unroll
    for (int s = 0; s < 2; ++s)
#pragma unroll
      for (int mi = 0; mi < 4; ++mi)
#pragma unroll
        for (int ni = 0; ni < 2; ++ni)
          acc[mi][ni] = __builtin_amdgcn_mfma_f32_16x16x32_bf16(a[s][mi], b[s][ni],
                                                                acc[mi][ni], 0, 0, 0);
    __syncthreads();
  }

  // epilogue: C row = m0+mi*16+qr*4+r, col = n0+wv*32+ni*16+lr
#pragma unroll
  for (int mi = 0; mi < 4; ++mi) {
#pragma unroll
    for (int ni = 0; ni < 2; ++ni) {
      const int col = n0 + wv * 32 + ni * 16 + lr;
      const float bv = bias ? bias[col] : 0.0f;
#pragma unroll
      for (int r = 0; r < 4; ++r) {
        const int row = m0 + mi * 16 + qr * 4 + r;
        const float val = acc[mi][ni][r] + bv;
        if (BF16_OUT)
          ((unsigned short*)Cout)[(size_t)row * N + col] = f2bf(val);
        else
          ((float*)Cout)[(size_t)row * N + col] = val;
      }
    }
  }
}

extern "C" void kernel_launch(void* const* d_in, const int* in_sizes, int n_in,
                              void* d_out, int out_size, void* d_ws, size_t ws_size,
                              hipStream_t stream) {
  const float* x      = (const float*)d_in[0];  // [4,1024,1024]
  const float* w_qkv  = (const float*)d_in[1];  // [1024,3072]
  const float* b_qkv  = (const float*)d_in[2];  // [3072]
  const float* w_proj = (const float*)d_in[3];  // [1024,1024]
  const float* b_proj = (const float*)d_in[4];  // [1024]
  // d_in[5]=rel_table, d_in[6]=rel_index unused (softmax rows sum to 1).
  float* out = (float*)d_out;

  char* ws = (char*)d_ws;
  unsigned short* xb  = (unsigned short*)(ws);                       // 8 MB [4096,1024]
  unsigned short* WpT = (unsigned short*)(ws + (size_t)(8u << 20));  // 2 MB WpT[n][j]=w_proj[j][n]
  unsigned short* Wvb = (unsigned short*)(ws + (size_t)(10u << 20)); // 2 MB Wvb[k][j]=w_qkv[k][2048+j]
  unsigned short* WcT = (unsigned short*)(ws + (size_t)(12u << 20)); // 2 MB WcT[n][k]=W_c[k][n]
  float*          b_c = (float*)(ws + (size_t)(14u << 20));          // 4 KB

  // 1. x -> bf16
  cast_bf16_kernel<<<(MTOT * DIMC) / (256 * 4), 256, 0, stream>>>(x, xb);
  // 2. WpT[n][j] = w_proj[j][n] (bf16, transposed)
  transpose_cast_kernel<<<dim3(32, 32), 256, 0, stream>>>(w_proj, DIMC, 0, WpT);
  // 3. Wvb[k][j] = w_qkv[k][2048+j] (bf16, row-major slice)
  cast_slice_kernel<<<(DIMC * DIMC) / (256 * 4), 256, 0, stream>>>(w_qkv, 3 * DIMC, 2 * DIMC, Wvb);
  // 4. b_c = Wproj^T b_v + b_proj
  bias_combine_kernel<<<DIMC / 64, 256, 0, stream>>>(b_qkv + 2 * DIMC, w_proj, b_proj, b_c);
  // 5. WcT[n][k] = sum_j WpT[n][j] * Wvb[k][j]  (= (Wv @ Wproj)^T, bf16 out)
  gemm_bt_kernel<true><<<dim3(DIMC / 128, DIMC / 64), 256, 0, stream>>>(
      WpT, Wvb, nullptr, WcT, DIMC, DIMC, DIMC);
  // 6. out = xb @ WcT^T + b_c  (fp32 out)
  gemm_bt_kernel<false><<<dim3(DIMC / 128, MTOT / 64), 256, 0, stream>>>(
      xb, WcT, b_c, out, MTOT, DIMC, DIMC);
}

// Round 3
// 132.301 us; speedup vs baseline: 1.4468x; 1.4468x over previous
//
#include <hip/hip_runtime.h>

// SimpleRelativeAttention collapses twice:
// 1. einsum 'bnqk,bnqe->bnqe' multiplies v by softmax row-sums (==1) -> attention
//    is an identity on v. rel_table/rel_index/q/k are dead.
// 2. out = x @ Wv @ Wproj + (b_v @ Wproj + b_proj); fold W_c = Wv @ Wproj
//    (1024^3 mini-GEMM) so the hot path is ONE 4096x1024x1024 GEMM.

#define DIMC 1024
#define MTOT 4096   // BATCH * SEQ

__device__ __forceinline__ unsigned short f2bf(float f) {
  unsigned u = __float_as_uint(f);
  u += 0x7FFFu + ((u >> 16) & 1u);   // round-to-nearest-even
  return (unsigned short)(u >> 16);
}

typedef __attribute__((ext_vector_type(8))) short short8;
typedef __attribute__((ext_vector_type(4))) float floatx4;

__device__ __forceinline__ void async_copy16(const unsigned short* g, unsigned short* l) {
  __builtin_amdgcn_global_load_lds(
      (const __attribute__((address_space(1))) unsigned int*)g,
      (__attribute__((address_space(3))) unsigned int*)l,
      16, 0, 0);
}

// fp32 -> bf16 elementwise, 4 elems/thread (contiguous)
__global__ void cast_bf16_kernel(const float* __restrict__ in,
                                 unsigned short* __restrict__ out) {
  int i = (blockIdx.x * 256 + threadIdx.x) * 4;
  float4 f = *(const float4*)(in + i);
  ushort4 o;
  o.x = f2bf(f.x); o.y = f2bf(f.y); o.z = f2bf(f.z); o.w = f2bf(f.w);
  *(ushort4*)(out + i) = o;
}

// out[r][c] = in[r*stride + col0 + c], out is [1024][1024] bf16 (no transpose)
__global__ void cast_slice_kernel(const float* __restrict__ in, int stride,
                                  int col0, unsigned short* __restrict__ out) {
  int i4 = blockIdx.x * 256 + threadIdx.x;      // one float4 per thread
  int r = i4 >> 8;                              // 256 groups of 4 per row
  int c = (i4 & 255) * 4;
  float4 f = *(const float4*)(in + (size_t)r * stride + col0 + c);
  ushort4 o;
  o.x = f2bf(f.x); o.y = f2bf(f.y); o.z = f2bf(f.z); o.w = f2bf(f.w);
  *(ushort4*)(out + (size_t)r * DIMC + c) = o;
}

// out[n][k] = in[k*stride + col0 + n]; out [DIMC][DIMC] bf16 row-major
__global__ void transpose_cast_kernel(const float* __restrict__ in, int stride,
                                      int col0, unsigned short* __restrict__ out) {
  __shared__ float tile[32][33];
  const int t = threadIdx.x;
  const int tx = t & 31, ty = t >> 5;
  const int bx = blockIdx.x, by = blockIdx.y;
#pragma unroll
  for (int r = 0; r < 4; ++r) {
    int kl = ty + r * 8;
    tile[kl][tx] = in[(size_t)(by * 32 + kl) * stride + col0 + bx * 32 + tx];
  }
  __syncthreads();
#pragma unroll
  for (int r = 0; r < 4; ++r) {
    int nl = ty + r * 8;
    out[(size_t)(bx * 32 + nl) * DIMC + by * 32 + tx] = f2bf(tile[tx][nl]);
  }
}

// Partial b_c[n] += sum_{j in tile} b_v[j] * w_proj[j][n].
// Grid (16 n-tiles of 64, 8 j-tiles of 128); 256 thr = 4 groups x 64 lanes,
// group q covers 32 j's; coalesced 256B row-segment reads; 8 atomicAdds/n.
// b_c must be zeroed before launch (hipMemsetAsync); b_proj added in GEMM epilogue.
__global__ void bias_partial_kernel(const float* __restrict__ b_v,
                                    const float* __restrict__ w_proj,
                                    float* __restrict__ b_c) {
  __shared__ float red[256];
  const int t = threadIdx.x;
  const int lane = t & 63, q = t >> 6;
  const int n = blockIdx.x * 64 + lane;
  const int j0 = blockIdx.y * 128 + q * 32;
  float s = 0.f;
#pragma unroll
  for (int i = 0; i < 32; ++i)
    s += b_v[j0 + i] * w_proj[(size_t)(j0 + i) * DIMC + n];
  red[t] = s;
  __syncthreads();
  if (q == 0) atomicAdd(&b_c[n], red[t] + red[t + 64] + red[t + 128] + red[t + 192]);
}

// C[M,N] = A[M,K] @ Bt[N,K]^T (+ bias[N] + bias2[N])
// 64x128 block tile, BK=64, 256 threads = 4 waves, each wave 64x32 (4x2 frags).
// LDS chunk layout is forced by global_load_lds (chunk c -> offset c*16B), so
// bank conflicts are broken by XOR-swizzling the k-chunk on the GLOBAL side:
// chunk c holds global (row=c>>3, kc=(c&7)^(row&7)). Fragment reads then hit
// all 32 banks (2-way alias only, free per m136), staging stays coalesced
// (permutation within a 128B row segment).
template <bool BF16_OUT>
__global__ __launch_bounds__(256, 2) void gemm_bt_kernel(
    const unsigned short* __restrict__ A,   // [M,K] bf16
    const unsigned short* __restrict__ Bt,  // [N,K] bf16
    const float* __restrict__ bias,         // [N] or nullptr
    const float* __restrict__ bias2,        // [N] or nullptr
    void* __restrict__ Cout, int M, int N, int K) {
  __shared__ __align__(16) unsigned short As[64 * 64];    // 8 KB
  __shared__ __align__(16) unsigned short Bs[128 * 64];   // 16 KB
  const int tid = threadIdx.x;
  const int wv = tid >> 6;
  const int lane = tid & 63;
  const int m0 = blockIdx.y * 64;
  const int n0 = blockIdx.x * 128;

  floatx4 acc[4][2] = {};

  // swizzled k-chunk for staging (row-invariant: offsets step rows by 32)
  const int srow = tid >> 3;                       // 0..31
  const int skc = (tid & 7) ^ (srow & 7);          // swizzled k-chunk 0..7
  const unsigned short* Ag0 = A + (size_t)(m0 + srow) * K + skc * 8;
  const unsigned short* Ag1 = A + (size_t)(m0 + 32 + srow) * K + skc * 8;
  const unsigned short* Bg0 = Bt + (size_t)(n0 + srow) * K + skc * 8;
  const unsigned short* Bg1 = Bt + (size_t)(n0 + 32 + srow) * K + skc * 8;
  const unsigned short* Bg2 = Bt + (size_t)(n0 + 64 + srow) * K + skc * 8;
  const unsigned short* Bg3 = Bt + (size_t)(n0 + 96 + srow) * K + skc * 8;
  unsigned short* AsW0 = As + (0 * 256 + wv * 64) * 8;   // HW adds lane*16B
  unsigned short* AsW1 = As + (1 * 256 + wv * 64) * 8;
  unsigned short* BsW0 = Bs + (0 * 256 + wv * 64) * 8;
  unsigned short* BsW1 = Bs + (1 * 256 + wv * 64) * 8;
  unsigned short* BsW2 = Bs + (2 * 256 + wv * 64) * 8;
  unsigned short* BsW3 = Bs + (3 * 256 + wv * 64) * 8;

  const int lr = lane & 15;
  const int qr = lane >> 4;
  const int lx = lr & 7;   // swizzle key for fragment reads

  for (int k0 = 0; k0 < K; k0 += 64) {
    async_copy16(Ag0 + k0, AsW0);
    async_copy16(Ag1 + k0, AsW1);
    async_copy16(Bg0 + k0, BsW0);
    async_copy16(Bg1 + k0, BsW1);
    async_copy16(Bg2 + k0, BsW2);
    async_copy16(Bg3 + k0, BsW3);
    __syncthreads();   // drains vmcnt before barrier

    short8 a[2][4], b[2][2];
#pragma unroll
    for (int s = 0; s < 2; ++s) {
      const int kphys = ((s * 4 + qr) ^ lx) * 8;
#pragma unroll
      for (int mi = 0; mi < 4; ++mi)
        a[s][mi] = *(const short8*)(As + (mi * 16 + lr) * 64 + kphys);
#pragma unroll
      for (int ni = 0; ni < 2; ++ni)
        b[s][ni] = *(const short8*)(Bs + (wv * 32 + ni * 16 + lr) * 64 + kphys);
    }
#pragma unroll
    for (int s = 0; s < 2; ++s)
#pragma unroll
      for (int mi = 0; mi < 4; ++mi)
#pragma unroll
        for (int ni = 0; ni < 2; ++ni)
          acc[mi][ni] = __builtin_amdgcn_mfma_f32_16x16x32_bf16(a[s][mi], b[s][ni],
                                                                acc[mi][ni], 0, 0, 0);
    __syncthreads();
  }

  // epilogue: C row = m0+mi*16+qr*4+r, col = n0+wv*32+ni*16+lr
#pragma unroll
  for (int mi = 0; mi < 4; ++mi) {
#pragma unroll
    for (int ni = 0; ni < 2; ++ni) {
      const int col = n0 + wv * 32 + ni * 16 + lr;
      float bv = 0.0f;
      if (bias)  bv += bias[col];
      if (bias2) bv += bias2[col];
#pragma unroll
      for (int r = 0; r < 4; ++r) {
        const int row = m0 + mi * 16 + qr * 4 + r;
        const float val = acc[mi][ni][r] + bv;
        if (BF16_OUT)
          ((unsigned short*)Cout)[(size_t)row * N + col] = f2bf(val);
        else
          ((float*)Cout)[(size_t)row * N + col] = val;
      }
    }
  }
}

extern "C" void kernel_launch(void* const* d_in, const int* in_sizes, int n_in,
                              void* d_out, int out_size, void* d_ws, size_t ws_size,
                              hipStream_t stream) {
  const float* x      = (const float*)d_in[0];  // [4,1024,1024]
  const float* w_qkv  = (const float*)d_in[1];  // [1024,3072]
  const float* b_qkv  = (const float*)d_in[2];  // [3072]
  const float* w_proj = (const float*)d_in[3];  // [1024,1024]
  const float* b_proj = (const float*)d_in[4];  // [1024]
  // d_in[5]=rel_table, d_in[6]=rel_index unused (softmax rows sum to 1).
  float* out = (float*)d_out;

  char* ws = (char*)d_ws;
  unsigned short* xb  = (unsigned short*)(ws);                       // 8 MB [4096,1024]
  unsigned short* WpT = (unsigned short*)(ws + (size_t)(8u << 20));  // 2 MB WpT[n][j]=w_proj[j][n]
  unsigned short* Wvb = (unsigned short*)(ws + (size_t)(10u << 20)); // 2 MB Wvb[k][j]=w_qkv[k][2048+j]
  unsigned short* WcT = (unsigned short*)(ws + (size_t)(12u << 20)); // 2 MB WcT[n][k]=W_c[k][n]
  float*          b_c = (float*)(ws + (size_t)(14u << 20));          // 4 KB

  // 1. x -> bf16
  cast_bf16_kernel<<<(MTOT * DIMC) / (256 * 4), 256, 0, stream>>>(x, xb);
  // 2. WpT[n][j] = w_proj[j][n] (bf16, transposed)
  transpose_cast_kernel<<<dim3(32, 32), 256, 0, stream>>>(w_proj, DIMC, 0, WpT);
  // 3. Wvb[k][j] = w_qkv[k][2048+j] (bf16, row-major slice)
  cast_slice_kernel<<<(DIMC * DIMC) / (256 * 4), 256, 0, stream>>>(w_qkv, 3 * DIMC, 2 * DIMC, Wvb);
  // 4. b_c = Wproj^T b_v  (zero-init + 128-block coalesced partial reduction)
  hipMemsetAsync(b_c, 0, DIMC * sizeof(float), stream);
  bias_partial_kernel<<<dim3(16, 8), 256, 0, stream>>>(b_qkv + 2 * DIMC, w_proj, b_c);
  // 5. WcT[n][k] = sum_j WpT[n][j] * Wvb[k][j]  (= (Wv @ Wproj)^T, bf16 out)
  gemm_bt_kernel<true><<<dim3(DIMC / 128, DIMC / 64), 256, 0, stream>>>(
      WpT, Wvb, nullptr, nullptr, WcT, DIMC, DIMC, DIMC);
  // 6. out = xb @ WcT^T + (b_c + b_proj)  (fp32 out)
  gemm_bt_kernel<false><<<dim3(DIMC / 128, MTOT / 64), 256, 0, stream>>>(
      xb, WcT, b_c, b_proj, out, MTOT, DIMC, DIMC);
}

// Round 4
// 128.730 us; speedup vs baseline: 1.4869x; 1.0277x over previous
//
#include <hip/hip_runtime.h>

// SimpleRelativeAttention collapses twice:
// 1. einsum 'bnqk,bnqe->bnqe' multiplies v by softmax row-sums (==1) -> attention
//    is an identity on v. rel_table/rel_index/q/k are dead.
// 2. out = x @ Wv @ Wproj + (b_v @ Wproj + b_proj); fold W_c = Wv @ Wproj
//    (1024^3 mini-GEMM) so the hot path is ONE 4096x1024x1024 GEMM.
// Timed window includes ~88us of harness poison/restore overhead (rocprof:
// fillBufferAligned 268MB @43us each); our controllable budget is the ~44us
// of kernel time. This round: 128x128 main GEMM (m97 config), 64x64 gemm1
// (full-GPU grid), fused prep kernel.

#define DIMC 1024
#define MTOT 4096   // BATCH * SEQ

__device__ __forceinline__ unsigned short f2bf(float f) {
  unsigned u = __float_as_uint(f);
  u += 0x7FFFu + ((u >> 16) & 1u);   // round-to-nearest-even
  return (unsigned short)(u >> 16);
}

typedef __attribute__((ext_vector_type(8))) short short8;
typedef __attribute__((ext_vector_type(4))) float floatx4;

__device__ __forceinline__ void async_copy16(const unsigned short* g, unsigned short* l) {
  __builtin_amdgcn_global_load_lds(
      (const __attribute__((address_space(1))) unsigned int*)g,
      (__attribute__((address_space(3))) unsigned int*)l,
      16, 0, 0);
}

// fp32 -> bf16 elementwise, 4 elems/thread (contiguous)
__global__ void cast_bf16_kernel(const float* __restrict__ in,
                                 unsigned short* __restrict__ out) {
  int i = (blockIdx.x * 256 + threadIdx.x) * 4;
  float4 f = *(const float4*)(in + i);
  ushort4 o;
  o.x = f2bf(f.x); o.y = f2bf(f.y); o.z = f2bf(f.z); o.w = f2bf(f.w);
  *(ushort4*)(out + i) = o;
}

// Fused weight prep, grid (32,32) x 256 thr. Block (bx,by):
//  - WpT[n][j] = w_proj[j][n] for j in by-tile, n in bx-tile (LDS transpose)
//  - Wvb[k][j2] = w_qkv[k][2048+j2] for k in by-tile, j2 in bx-tile (cast)
//  - b_c[n] += sum_{j in by-tile} b_v[j] * w_proj[j][n] (reuses LDS tile;
//    b_c zeroed by hipMemsetAsync; b_proj added in main GEMM epilogue)
__global__ void prep_kernel(const float* __restrict__ w_proj,
                            const float* __restrict__ w_qkv,
                            const float* __restrict__ b_v,
                            unsigned short* __restrict__ WpT,
                            unsigned short* __restrict__ Wvb,
                            float* __restrict__ b_c) {
  __shared__ float tile[32][33];
  const int t = threadIdx.x;
  const int tx = t & 31, ty = t >> 5;
  const int bx = blockIdx.x, by = blockIdx.y;
#pragma unroll
  for (int r = 0; r < 4; ++r) {
    int kl = ty + r * 8;
    tile[kl][tx] = w_proj[(size_t)(by * 32 + kl) * DIMC + bx * 32 + tx];
  }
  {  // w_qkv slice cast (independent of LDS)
    const int r2 = t >> 3, c4 = (t & 7) * 4;
    float4 f = *(const float4*)(w_qkv + (size_t)(by * 32 + r2) * (3 * DIMC) +
                                2 * DIMC + bx * 32 + c4);
    ushort4 o;
    o.x = f2bf(f.x); o.y = f2bf(f.y); o.z = f2bf(f.z); o.w = f2bf(f.w);
    *(ushort4*)(Wvb + (size_t)(by * 32 + r2) * DIMC + bx * 32 + c4) = o;
  }
  __syncthreads();
#pragma unroll
  for (int r = 0; r < 4; ++r) {
    int nl = ty + r * 8;
    WpT[(size_t)(bx * 32 + nl) * DIMC + by * 32 + tx] = f2bf(tile[tx][nl]);
  }
  if (t < 32) {
    float s = 0.f;
#pragma unroll
    for (int kl = 0; kl < 32; ++kl) s += b_v[by * 32 + kl] * tile[kl][t];
    atomicAdd(&b_c[bx * 32 + t], s);
  }
}

// C[M,N] = A[M,K] @ Bt[N,K]^T (+ bias[N] + bias2[N])
// BM x BN block tile, BK=64, 256 threads = 4 waves in 2x2, wave tile
// (BM/2)x(BN/2), 16x16x32 bf16 MFMA. global_load_lds width-16 staging with
// global-side XOR swizzle of the k-chunk (chunk c holds row=c>>3,
// kc=(c&7)^(row&7)) so ds_read_b128 fragment reads are bank-conflict-free
// while staging stays coalesced (permutation within a 128B row segment).
// SWZ: XCD-aware 1D-grid decode so each XCD keeps a narrow A row-range +
// all of B in its private L2 (speed heuristic only).
template <int BM, int BN, bool BF16_OUT, bool SWZ>
__global__ __launch_bounds__(256, 2) void gemm_bt_kernel(
    const unsigned short* __restrict__ A,   // [M,K] bf16
    const unsigned short* __restrict__ Bt,  // [N,K] bf16
    const float* __restrict__ bias,         // [N] or nullptr
    const float* __restrict__ bias2,        // [N] or nullptr
    void* __restrict__ Cout, int M, int N, int K, int gx) {
  constexpr int MI = BM / 32;   // m-frags per wave
  constexpr int NI = BN / 32;   // n-frags per wave
  constexpr int AG = BM / 32;   // A staging glls per thread
  constexpr int BG = BN / 32;   // B staging glls per thread
  __shared__ __align__(16) unsigned short As[BM * 64];
  __shared__ __align__(16) unsigned short Bs[BN * 64];

  const int tid = threadIdx.x;
  const int wv = tid >> 6;
  const int lane = tid & 63;

  int bx, by;
  if (SWZ) {  // 256 blocks: xcd = bid&7 gets x=all, y in [4*xcd, 4*xcd+4)
    const int bid = blockIdx.x;
    bx = (bid >> 3) & 7;
    by = (bid & 7) * 4 + (bid >> 6);
  } else {
    bx = blockIdx.x % gx;
    by = blockIdx.x / gx;
  }
  const int m0 = by * BM;
  const int n0 = bx * BN;

  floatx4 acc[MI][NI] = {};

  // staging addresses (swizzled k-chunk; row-invariant since rows step by 32)
  const int srow = tid >> 3;                 // 0..31
  const int skc = (tid & 7) ^ (srow & 7);    // swizzled k-chunk
  const unsigned short* Ag[AG];
  const unsigned short* Bg[BG];
#pragma unroll
  for (int g = 0; g < AG; ++g)
    Ag[g] = A + (size_t)(m0 + g * 32 + srow) * K + skc * 8;
#pragma unroll
  for (int g = 0; g < BG; ++g)
    Bg[g] = Bt + (size_t)(n0 + g * 32 + srow) * K + skc * 8;

  const int lr = lane & 15;
  const int qr = lane >> 4;
  const int lx = lr & 7;                     // fragment-read swizzle key
  const int wrow = (wv >> 1) * (BM / 2);
  const int wcol = (wv & 1) * (BN / 2);

  for (int k0 = 0; k0 < K; k0 += 64) {
#pragma unroll
    for (int g = 0; g < AG; ++g)
      async_copy16(Ag[g] + k0, As + (g * 256 + wv * 64) * 8);
#pragma unroll
    for (int g = 0; g < BG; ++g)
      async_copy16(Bg[g] + k0, Bs + (g * 256 + wv * 64) * 8);
    __syncthreads();   // drains vmcnt before barrier

    short8 a[2][MI], b[2][NI];
#pragma unroll
    for (int s = 0; s < 2; ++s) {
      const int kphys = ((s * 4 + qr) ^ lx) * 8;
#pragma unroll
      for (int mi = 0; mi < MI; ++mi)
        a[s][mi] = *(const short8*)(As + (wrow + mi * 16 + lr) * 64 + kphys);
#pragma unroll
      for (int ni = 0; ni < NI; ++ni)
        b[s][ni] = *(const short8*)(Bs + (wcol + ni * 16 + lr) * 64 + kphys);
    }
#pragma unroll
    for (int s = 0; s < 2; ++s)
#pragma unroll
      for (int mi = 0; mi < MI; ++mi)
#pragma unroll
        for (int ni = 0; ni < NI; ++ni)
          acc[mi][ni] = __builtin_amdgcn_mfma_f32_16x16x32_bf16(a[s][mi], b[s][ni],
                                                                acc[mi][ni], 0, 0, 0);
    __syncthreads();
  }

  // epilogue: C row = m0+wrow+mi*16+qr*4+r, col = n0+wcol+ni*16+lr
#pragma unroll
  for (int mi = 0; mi < MI; ++mi) {
#pragma unroll
    for (int ni = 0; ni < NI; ++ni) {
      const int col = n0 + wcol + ni * 16 + lr;
      float bv = 0.0f;
      if (bias)  bv += bias[col];
      if (bias2) bv += bias2[col];
#pragma unroll
      for (int r = 0; r < 4; ++r) {
        const int row = m0 + wrow + mi * 16 + qr * 4 + r;
        const float val = acc[mi][ni][r] + bv;
        if (BF16_OUT)
          ((unsigned short*)Cout)[(size_t)row * N + col] = f2bf(val);
        else
          ((float*)Cout)[(size_t)row * N + col] = val;
      }
    }
  }
}

extern "C" void kernel_launch(void* const* d_in, const int* in_sizes, int n_in,
                              void* d_out, int out_size, void* d_ws, size_t ws_size,
                              hipStream_t stream) {
  const float* x      = (const float*)d_in[0];  // [4,1024,1024]
  const float* w_qkv  = (const float*)d_in[1];  // [1024,3072]
  const float* b_qkv  = (const float*)d_in[2];  // [3072]
  const float* w_proj = (const float*)d_in[3];  // [1024,1024]
  const float* b_proj = (const float*)d_in[4];  // [1024]
  // d_in[5]=rel_table, d_in[6]=rel_index unused (softmax rows sum to 1).
  float* out = (float*)d_out;

  char* ws = (char*)d_ws;
  unsigned short* xb  = (unsigned short*)(ws);                       // 8 MB [4096,1024]
  unsigned short* WpT = (unsigned short*)(ws + (size_t)(8u << 20));  // 2 MB WpT[n][j]=w_proj[j][n]
  unsigned short* Wvb = (unsigned short*)(ws + (size_t)(10u << 20)); // 2 MB Wvb[k][j]=w_qkv[k][2048+j]
  unsigned short* WcT = (unsigned short*)(ws + (size_t)(12u << 20)); // 2 MB WcT[n][k]=W_c[k][n]
  float*          b_c = (float*)(ws + (size_t)(14u << 20));          // 4 KB

  // 1. b_c zero-init (prep_kernel atomicAdds into it)
  hipMemsetAsync(b_c, 0, DIMC * sizeof(float), stream);
  // 2. x -> bf16
  cast_bf16_kernel<<<(MTOT * DIMC) / (256 * 4), 256, 0, stream>>>(x, xb);
  // 3. fused: WpT transpose-cast, Wvb slice-cast, b_c partial matvec
  prep_kernel<<<dim3(32, 32), 256, 0, stream>>>(w_proj, w_qkv, b_qkv + 2 * DIMC,
                                                WpT, Wvb, b_c);
  // 4. WcT[n][k] = sum_j WpT[n][j] * Wvb[k][j]  (64x64 tile, 256 blocks)
  gemm_bt_kernel<64, 64, true, false><<<256, 256, 0, stream>>>(
      WpT, Wvb, nullptr, nullptr, WcT, DIMC, DIMC, DIMC, DIMC / 64);
  // 5. out = xb @ WcT^T + (b_c + b_proj)  (128x128 tile, 256 blocks, XCD swizzle)
  gemm_bt_kernel<128, 128, false, true><<<256, 256, 0, stream>>>(
      xb, WcT, b_c, b_proj, out, MTOT, DIMC, DIMC, DIMC / 128);
}